// Round 1
// 422.025 us; speedup vs baseline: 1.0966x; 1.0966x over previous
//
#include <hip/hip_runtime.h>
#include <stdint.h>

// ---------------------------------------------------------------------------
// FineReviewDecoderAttention: cvt f32->bf16 -> q/k/v proj (bf16 MFMA GEMM,
// counted-vmcnt 2-buffer pipeline + T2 bank-swizzle) -> fused attention ->
// out proj.  B=32 Q=128 D=1024 H=16 d=64 R=20 T=64.
// Delta vs round 13 (passed, 462.8us): attn2 skips reviews whose pooled
// weight is provably exactly 0.0f.  Reference: when any review in row b has
// mask==0, reviews with mask==1 get e += -1e30; expf(-1e30 - max) underflows
// to 0.0f in f32, so their numerator/denominator contribution is exactly 0.
// We build a 20-bit active-review bitmask (uniform per block -> no
// divergence, uniform barrier count) and iterate only active reviews with
// the same double-buffered K/V staging pipeline (stage NEXT ACTIVE review
// under current review's compute).  E[active] = 10/20 for this input dist;
// bit-exact for any input.  GEMMs / cvt kernels unchanged.
// ---------------------------------------------------------------------------

typedef __attribute__((ext_vector_type(8))) short bf16x8;
typedef __attribute__((ext_vector_type(4))) float f32x4;
typedef __attribute__((ext_vector_type(4))) unsigned int u32x4;
typedef __attribute__((address_space(1))) const unsigned int as1_t;
typedef __attribute__((address_space(3))) unsigned int as3_t;

#define DEVI static __device__ __forceinline__

DEVI unsigned short f2bf(float f) {  // RNE f32->bf16 (finite inputs)
  unsigned int u = __float_as_uint(f);
  u += 0x7fffu + ((u >> 16) & 1u);
  return (unsigned short)(u >> 16);
}
DEVI unsigned int pack2(float a, float b) {
  return (unsigned int)f2bf(a) | ((unsigned int)f2bf(b) << 16);
}
// Round-half-up bf16 pair pack (proven rounds 7-12): a -> lo16, b -> hi16.
DEVI unsigned int pk2_rhu(float a, float b) {
  unsigned int ua = __float_as_uint(a) + 0x8000u;
  unsigned int ub = __float_as_uint(b) + 0x8000u;
  return (ua >> 16) | (ub & 0xffff0000u);
}

DEVI void gload_lds16(const void* g, void* l) {
  __builtin_amdgcn_global_load_lds((as1_t*)g, (as3_t*)l, 16, 0, 0);
}

DEVI float fast_tanh(float x) {  // round-5-proven form
  float ax = fabsf(x);
  float e = __expf(2.0f * ax);
  float r = __builtin_fmaf(-2.0f, __builtin_amdgcn_rcpf(e + 1.0f), 1.0f);
  return copysignf(r, x);
}

// ------------------------- weight f32 -> bf16 ------------------------------
__global__ void cvt_w4(const float* __restrict__ w0, const float* __restrict__ w1,
                       const float* __restrict__ w2, const float* __restrict__ w3,
                       unsigned short* __restrict__ o0, unsigned short* __restrict__ o1,
                       unsigned short* __restrict__ o2, unsigned short* __restrict__ o3) {
  int i = blockIdx.x * 256 + threadIdx.x;
  if (i >= 262144) return;
  f32x4 v;
  uint2 a;
  v = ((const f32x4*)w0)[i]; a.x = pack2(v[0], v[1]); a.y = pack2(v[2], v[3]);
  *(uint2*)(o0 + 4 * (size_t)i) = a;
  v = ((const f32x4*)w1)[i]; a.x = pack2(v[0], v[1]); a.y = pack2(v[2], v[3]);
  *(uint2*)(o1 + 4 * (size_t)i) = a;
  v = ((const f32x4*)w2)[i]; a.x = pack2(v[0], v[1]); a.y = pack2(v[2], v[3]);
  *(uint2*)(o2 + 4 * (size_t)i) = a;
  v = ((const f32x4*)w3)[i]; a.x = pack2(v[0], v[1]); a.y = pack2(v[2], v[3]);
  *(uint2*)(o3 + 4 * (size_t)i) = a;
}

// --------------------- activation f32 -> bf16 stream -----------------------
__global__ void cvt_bf16(const float* __restrict__ src,
                         unsigned short* __restrict__ dst, int n8) {
  const int stride = (int)(gridDim.x * blockDim.x);
  for (int i = (int)(blockIdx.x * blockDim.x + threadIdx.x); i < n8; i += stride) {
    f32x4 a = ((const f32x4*)src)[2 * i];
    f32x4 b = ((const f32x4*)src)[2 * i + 1];
    u32x4 o = {pack2(a[0], a[1]), pack2(a[2], a[3]), pack2(b[0], b[1]), pack2(b[2], b[3])};
    ((u32x4*)dst)[i] = o;
  }
}

// ---------------- C[m,n] = sum_k A[m,k]*W[n,k] + bias[n] -------------------
// OUT_MODE: 0 = f32 row-major, 1 = bf16 row-major, 2 = bf16 per-head V^T.
// ABF=1: counted-vmcnt 2-buffer pipeline, bank-swizzled LDS tiles.
// ABF=0: f32-A 2-phase fallback (linear LDS). SC=1: epilogue x0.125.
template <int OUT_MODE, int ABF, int SC>
__global__ __launch_bounds__(256, 4) void gemm_bt(
    const void* __restrict__ Ain, const unsigned short* __restrict__ W,
    const float* __restrict__ bias, void* __restrict__ Cout, int N, int K, int nnt) {
  __shared__ unsigned short As[2][128 * 32];
  __shared__ unsigned short Bs[2][128 * 32];
  const int tid = (int)threadIdx.x;
  const int lane = tid & 63, wave = tid >> 6;
  const int lm = lane & 15, l4 = lane >> 4;
  const int nb = (int)gridDim.x;
  const int bx = (int)blockIdx.x;
  const int lg = (bx & 7) * (nb >> 3) + (bx >> 3);
  const int mt = lg / nnt, nt = lg % nnt;
  const int wr = wave >> 1, wc = wave & 1;

  f32x4 zero4 = {0.f, 0.f, 0.f, 0.f};
  f32x4 acc[4][4];
#pragma unroll
  for (int i = 0; i < 4; ++i)
#pragma unroll
    for (int j = 0; j < 4; ++j) acc[i][j] = zero4;

  char* Asb = (char*)As;
  char* Bsb = (char*)Bs;

  // staging thread mapping: row = tid>>2, 16B chunk = tid&3.
  const int srow = tid >> 2, sblk = tid & 3;
  // T2 swizzle: chunk (row,blk) lives at slot (row, blk ^ ((row>>1)&3)).
  // Linear LDS dest (tid*16) => pre-swizzle the GLOBAL column: scb.
  const int scb = ABF ? (sblk ^ ((srow >> 1) & 3)) : sblk;
  const unsigned short* apg =
      (const unsigned short*)Ain + (size_t)(mt * 128 + srow) * K + scb * 8;
  const unsigned short* wpg = W + (size_t)(nt * 128 + srow) * K + scb * 8;
  // fragment-read XOR key: ((row>>1)&3) with row = wr*64 + i*16 + lm -> only
  // lm's bits survive mod 4 => kx = (lm>>1)&3. 0 for the linear ABF=0 path.
  const int kx = ABF ? ((lm >> 1) & 3) : 0;

  const int arow = tid >> 1, acol = (tid & 1) * 16;
  const float* apf = (const float*)Ain + (size_t)(mt * 128 + arow) * K + acol;

  if (ABF) {
    // ---- counted-vmcnt pipeline: stage(t) = 4 gload_lds into buf ----
    const int NT = K >> 5;
#pragma unroll
    for (int t0 = 0; t0 < 2; ++t0) {
      const int kt = t0 * 32;
      gload_lds16(apg + kt, Asb + t0 * 8192 + tid * 16);
      gload_lds16(apg + (size_t)64 * K + kt, Asb + t0 * 8192 + 4096 + tid * 16);
      gload_lds16(wpg + kt, Bsb + t0 * 8192 + tid * 16);
      gload_lds16(wpg + (size_t)64 * K + kt, Bsb + t0 * 8192 + 4096 + tid * 16);
    }
    int cur = 0;
    for (int t = 0; t < NT; ++t) {
      if (t + 1 < NT)
        asm volatile("s_waitcnt vmcnt(4)" ::: "memory");
      else
        asm volatile("s_waitcnt vmcnt(0)" ::: "memory");
      asm volatile("s_barrier" ::: "memory");
      bf16x8 af[4], bfr[4];
#pragma unroll
      for (int i = 0; i < 4; ++i)
        af[i] = *(const bf16x8*)(Asb + cur * 8192 + (wr * 64 + i * 16 + lm) * 64 +
                                 ((l4 ^ kx) * 16));
#pragma unroll
      for (int j = 0; j < 4; ++j)
        bfr[j] = *(const bf16x8*)(Bsb + cur * 8192 + (wc * 64 + j * 16 + lm) * 64 +
                                  ((l4 ^ kx) * 16));
#pragma unroll
      for (int i = 0; i < 4; ++i)
#pragma unroll
        for (int j = 0; j < 4; ++j)
          acc[i][j] = __builtin_amdgcn_mfma_f32_16x16x32_bf16(af[i], bfr[j], acc[i][j], 0, 0, 0);
      asm volatile("s_barrier" ::: "memory");
      if (t + 2 < NT) {
        const int kt = (t + 2) * 32;
        gload_lds16(apg + kt, Asb + cur * 8192 + tid * 16);
        gload_lds16(apg + (size_t)64 * K + kt, Asb + cur * 8192 + 4096 + tid * 16);
        gload_lds16(wpg + kt, Bsb + cur * 8192 + tid * 16);
        gload_lds16(wpg + (size_t)64 * K + kt, Bsb + cur * 8192 + 4096 + tid * 16);
      }
      cur ^= 1;
    }
  } else {
    // ---- f32-A fallback: round-9-proven 2-phase (linear LDS) ----
    f32x4 an[4];
#pragma unroll
    for (int u = 0; u < 4; ++u) an[u] = *(const f32x4*)(apf + u * 4);
    gload_lds16(wpg, Bsb + tid * 16);
    gload_lds16(wpg + (size_t)64 * K, Bsb + 4096 + tid * 16);
    {
      u32x4 lo = {pk2_rhu(an[0][0], an[0][1]), pk2_rhu(an[0][2], an[0][3]),
                  pk2_rhu(an[1][0], an[1][1]), pk2_rhu(an[1][2], an[1][3])};
      u32x4 hi = {pk2_rhu(an[2][0], an[2][1]), pk2_rhu(an[2][2], an[2][3]),
                  pk2_rhu(an[3][0], an[3][1]), pk2_rhu(an[3][2], an[3][3])};
      char* dst = Asb + arow * 64 + acol * 2;
      ((u32x4*)dst)[0] = lo;
      ((u32x4*)dst)[1] = hi;
      if (32 < K) {
#pragma unroll
        for (int u = 0; u < 4; ++u) an[u] = *(const f32x4*)(apf + 32 + u * 4);
      }
    }
    __syncthreads();
    int cur = 0;
    for (int kt = 0; kt < K; kt += 32) {
      const int nxt = cur ^ 1;
      if (kt + 32 < K) {
        gload_lds16(wpg + (kt + 32), Bsb + nxt * 8192 + tid * 16);
        gload_lds16(wpg + (size_t)64 * K + (kt + 32), Bsb + nxt * 8192 + 4096 + tid * 16);
        u32x4 lo = {pk2_rhu(an[0][0], an[0][1]), pk2_rhu(an[0][2], an[0][3]),
                    pk2_rhu(an[1][0], an[1][1]), pk2_rhu(an[1][2], an[1][3])};
        u32x4 hi = {pk2_rhu(an[2][0], an[2][1]), pk2_rhu(an[2][2], an[2][3]),
                    pk2_rhu(an[3][0], an[3][1]), pk2_rhu(an[3][2], an[3][3])};
        char* dst = Asb + nxt * 8192 + arow * 64 + acol * 2;
        ((u32x4*)dst)[0] = lo;
        ((u32x4*)dst)[1] = hi;
        if (kt + 64 < K) {
#pragma unroll
          for (int u = 0; u < 4; ++u) an[u] = *(const f32x4*)(apf + (kt + 64) + u * 4);
        }
      }
      bf16x8 af[4], bfr[4];
#pragma unroll
      for (int i = 0; i < 4; ++i)
        af[i] = *(const bf16x8*)(Asb + cur * 8192 + (wr * 64 + i * 16 + lm) * 64 + l4 * 16);
#pragma unroll
      for (int j = 0; j < 4; ++j)
        bfr[j] = *(const bf16x8*)(Bsb + cur * 8192 + (wc * 64 + j * 16 + lm) * 64 + l4 * 16);
#pragma unroll
      for (int i = 0; i < 4; ++i)
#pragma unroll
        for (int j = 0; j < 4; ++j)
          acc[i][j] = __builtin_amdgcn_mfma_f32_16x16x32_bf16(af[i], bfr[j], acc[i][j], 0, 0, 0);
      __syncthreads();
      cur = nxt;
    }
  }

  const int r0 = mt * 128 + wr * 64 + l4 * 4;
  const int c0 = nt * 128 + wc * 64 + lm;
  float bb[4];
#pragma unroll
  for (int j = 0; j < 4; ++j) bb[j] = bias[c0 + j * 16];

  if (OUT_MODE < 2) {
#pragma unroll
    for (int i = 0; i < 4; ++i)
#pragma unroll
      for (int j = 0; j < 4; ++j)
#pragma unroll
        for (int p = 0; p < 4; ++p) {
          size_t idx = (size_t)(r0 + i * 16 + p) * N + (size_t)(c0 + j * 16);
          float v = acc[i][j][p] + bb[j];
          if (SC) v *= 0.125f;  // exact exponent shift; bf16(v/8) == bf16(v)/8
          if (OUT_MODE == 1)
            ((unsigned short*)Cout)[idx] = f2bf(v);
          else
            ((float*)Cout)[idx] = v;
        }
  } else {
    // V^T per-head tiles: vt[((b*20+r)*16+h)*4096 + d*64 + t], t = i*16+l4*4+p
    const int grow = mt * 128 + wr * 64;
    const int bidx = grow / 1280;
    const int rv = (grow % 1280) / 64;
    const int hh = (nt * 128 + wc * 64) / 64;
    unsigned short* vt = (unsigned short*)Cout;
    const size_t base = ((size_t)(bidx * 20 + rv) * 16 + hh) * 4096;
#pragma unroll
    for (int j = 0; j < 4; ++j) {
      const int d = lm + j * 16;
#pragma unroll
      for (int i = 0; i < 4; ++i) {
        uint2 wv;
        wv.x = pack2(acc[i][j][0] + bb[j], acc[i][j][1] + bb[j]);
        wv.y = pack2(acc[i][j][2] + bb[j], acc[i][j][3] + bb[j]);
        *(uint2*)(vt + base + (size_t)d * 64 + i * 16 + l4 * 4) = wv;
      }
    }
  }
}

// ----------------------------- fused attention -----------------------------
// One block per (h, b); 8 waves, wave w owns q rows [16w,16w+16).
// Swapped-operand MFMAs so q = lane&15 everywhere; online softmax over r.
// LDS (48KB): kv_s[2][K,V] 32KB; pa_s 16KB; q/sa^T staging overlays.
// Active-review compaction: reviews with mask==1 (when any mask==0 exists in
// row b) have pooled weight exactly 0.0f (expf(-1e30 - max) underflows) ->
// skipped entirely.  Bitmask is uniform per block (depends only on b).
__global__ __launch_bounds__(512, 4) void attn2(
    const unsigned short* __restrict__ qb, const unsigned short* __restrict__ kb,
    const unsigned short* __restrict__ vtg, const int* __restrict__ mask,
    const int* __restrict__ mask2, const float* __restrict__ sa_a,
    const float* __restrict__ sa_b, unsigned short* __restrict__ merged) {
  const int h = (int)blockIdx.x;
  const int b = (int)blockIdx.y;
  const int tid = (int)threadIdx.x;
  const int lane = tid & 63, wave = tid >> 6;
  const int lm = lane & 15, l4 = lane >> 4;
  const int sw = (lm & 7) << 4;

  __shared__ unsigned short kv_s[2][2][64 * 64];  // [buf][0=K [t][d], 1=V^T [d][t]]
  __shared__ unsigned short pa_s[8 * 16 * 64];    // wave-private P/att rows

  char* kvb0 = (char*)kv_s;          // buf stride 16384; V^T at +8192
  char* qreg = (char*)kv_s + 16384;  // q staging region = buf1 (dead after hoist)
  char* satb = (char*)pa_s;          // sa^T staging (dead after hoist)

  // ---- active-review bitmask (uniform across the block) ----
  unsigned am = 0u;
#pragma unroll
  for (int rr = 0; rr < 20; ++rr)
    am |= (mask[b * 20 + rr] == 0) ? (1u << rr) : 0u;
  // az (= some review has mask==0) => only those reviews survive; else all.
  const unsigned act = am ? am : 0xFFFFFu;

  // ---- stage Q into qreg (pre-swizzled source columns) ----
#pragma unroll
  for (int s = 0; s < 2; ++s) {
    int idx = s * 512 + tid, row = idx >> 3, blk = idx & 7;
    int cb = blk ^ (row & 7);
    gload_lds16(qb + (size_t)(b * 128 + row) * 1024 + h * 64 + cb * 8, qreg + idx * 16);
  }
  // ---- stage sa^T into satb: sat[jj][d] = sa_a[d][jj], swizzled ----
#pragma unroll
  for (int s = 0; s < 8; ++s) {
    int idx = s * 512 + tid, jj = idx & 63, d = idx >> 6;
    *(unsigned short*)(satb + jj * 128 + ((d * 2) ^ ((jj & 7) << 4))) =
        f2bf(sa_a[d * 64 + jj]);
  }
  // ---- stage first ACTIVE review K/V into buf0 ----
  const int srow = tid >> 3, sblk = tid & 7;
  const int scb = sblk ^ (srow & 7);
  int r = (int)__builtin_ctz(act);
  unsigned rem = act & (act - 1u);
  gload_lds16(kb + ((size_t)(b * 20 + r) * 64 + srow) * 1024 + h * 64 + scb * 8,
              kvb0 + tid * 16);
  gload_lds16(vtg + ((size_t)(b * 20 + r) * 16 + h) * 4096 + srow * 64 + scb * 8,
              kvb0 + 8192 + tid * 16);

  f32x4 sbv[4];
#pragma unroll
  for (int i = 0; i < 4; ++i) sbv[i] = *(const f32x4*)(sa_b + i * 16 + l4 * 4);

  __syncthreads();  // qreg, satb, buf0 all visible

  // ---- hoist Q B-fragments and sa^T A-fragments to registers ----
  const char* qrp = qreg + (wave * 16 + lm) * 128;
  bf16x8 qf[2];
  qf[0] = *(const bf16x8*)(qrp + ((l4 * 16) ^ sw));
  qf[1] = *(const bf16x8*)(qrp + ((64 + l4 * 16) ^ sw));
  bf16x8 sfr[2][4];
#pragma unroll
  for (int kk = 0; kk < 2; ++kk)
#pragma unroll
    for (int i = 0; i < 4; ++i)
      sfr[kk][i] = *(const bf16x8*)(satb + (i * 16 + lm) * 128 +
                                    ((kk * 64 + l4 * 16) ^ sw));
  asm volatile("s_waitcnt lgkmcnt(0)" ::: "memory");  // hoist reads retired
  __syncthreads();  // all waves done -> qreg/satb reusable as buf1 / P-rows

  char* pw = (char*)pa_s + wave * 2048 + lm * 128;  // wave-private row q=lm

  f32x4 zero4 = {0.f, 0.f, 0.f, 0.f};
  f32x4 Pacc[4];
#pragma unroll
  for (int i = 0; i < 4; ++i) Pacc[i] = zero4;
  float m_run = -3.0e38f, s_run = 0.0f;

  int it = 0;
  for (;;) {
    const int pb = it & 1;
    if (it) __syncthreads();  // buf[pb] staged; all waves done with buf[1-pb]
    const int nr = rem ? (int)__builtin_ctz(rem) : -1;
    if (nr >= 0) {  // stage next active review (flies under this one's compute)
      const int nbuf = pb ^ 1;
      gload_lds16(kb + ((size_t)(b * 20 + nr) * 64 + srow) * 1024 + h * 64 + scb * 8,
                  kvb0 + nbuf * 16384 + tid * 16);
      gload_lds16(vtg + ((size_t)(b * 20 + nr) * 16 + h) * 4096 + srow * 64 + scb * 8,
                  kvb0 + nbuf * 16384 + 8192 + tid * 16);
    }
    const char* kbse = kvb0 + pb * 16384;
    const char* vbse = kvb0 + pb * 16384 + 8192;

    // ---- S^T = mfma(K, Q): rows t, col q (q pre-scaled by 1/8) ----
    f32x4 sc[4];
#pragma unroll
    for (int i = 0; i < 4; ++i) sc[i] = zero4;
    __builtin_amdgcn_s_setprio(1);
#pragma unroll
    for (int kk = 0; kk < 2; ++kk) {
      bf16x8 kf[4];
#pragma unroll
      for (int i = 0; i < 4; ++i)
        kf[i] = *(const bf16x8*)(kbse + (i * 16 + lm) * 128 + ((kk * 64 + l4 * 16) ^ sw));
#pragma unroll
      for (int i = 0; i < 4; ++i)
        sc[i] = __builtin_amdgcn_mfma_f32_16x16x32_bf16(kf[i], qf[kk], sc[i], 0, 0, 0);
    }
    __builtin_amdgcn_s_setprio(0);

    // ---- token mask (scores already scaled) + softmax over t ----
    const int mbase = (b * 20 + r) * 64;
#pragma unroll
    for (int i = 0; i < 4; ++i) {
      int4 m2 = *(const int4*)(mask2 + mbase + i * 16 + l4 * 4);
      sc[i][0] = (m2.x == 0) ? -1e20f : sc[i][0];
      sc[i][1] = (m2.y == 0) ? -1e20f : sc[i][1];
      sc[i][2] = (m2.z == 0) ? -1e20f : sc[i][2];
      sc[i][3] = (m2.w == 0) ? -1e20f : sc[i][3];
    }
    float mx = sc[0][0];
#pragma unroll
    for (int i = 0; i < 4; ++i)
#pragma unroll
      for (int p = 0; p < 4; ++p) mx = fmaxf(mx, sc[i][p]);
    mx = fmaxf(mx, __shfl_xor(mx, 16));
    mx = fmaxf(mx, __shfl_xor(mx, 32));
    float sum = 0.f;
#pragma unroll
    for (int i = 0; i < 4; ++i)
#pragma unroll
      for (int p = 0; p < 4; ++p) {
        float e = __expf(sc[i][p] - mx);
        sc[i][p] = e;
        sum += e;
      }
    sum += __shfl_xor(sum, 16);
    sum += __shfl_xor(sum, 32);
    const float pinv = __builtin_amdgcn_rcpf(sum);

    // ---- P -> wave-private LDS [q][t], packed 8B swizzled writes ----
#pragma unroll
    for (int i = 0; i < 4; ++i) {
      uint2 wv;
      wv.x = pk2_rhu(sc[i][0] * pinv, sc[i][1] * pinv);
      wv.y = pk2_rhu(sc[i][2] * pinv, sc[i][3] * pinv);
      *(uint2*)(pw + ((i * 32 + l4 * 8) ^ sw)) = wv;
    }

    // ---- att^T = mfma(V^T, P): rows d, col q ----
    f32x4 av[4];
#pragma unroll
    for (int i = 0; i < 4; ++i) av[i] = zero4;
    __builtin_amdgcn_s_setprio(1);
#pragma unroll
    for (int kk = 0; kk < 2; ++kk) {
      bf16x8 pf = *(const bf16x8*)(pw + ((kk * 64 + l4 * 16) ^ sw));
      bf16x8 vf[4];
#pragma unroll
      for (int i = 0; i < 4; ++i)
        vf[i] = *(const bf16x8*)(vbse + (i * 16 + lm) * 128 + ((kk * 64 + l4 * 16) ^ sw));
#pragma unroll
      for (int i = 0; i < 4; ++i)
        av[i] = __builtin_amdgcn_mfma_f32_16x16x32_bf16(vf[i], pf, av[i], 0, 0, 0);
    }
    __builtin_amdgcn_s_setprio(0);

    // ---- att -> same wave-private LDS [q][d] (P already consumed) ----
#pragma unroll
    for (int i = 0; i < 4; ++i) {
      uint2 wv;
      wv.x = pk2_rhu(av[i][0], av[i][1]);
      wv.y = pk2_rhu(av[i][2], av[i][3]);
      *(uint2*)(pw + ((i * 32 + l4 * 8) ^ sw)) = wv;
    }

    // ---- e^T = mfma(sa^T, att): rows jj, col q ----
    f32x4 ep[4];
#pragma unroll
    for (int i = 0; i < 4; ++i) ep[i] = zero4;
    __builtin_amdgcn_s_setprio(1);
#pragma unroll
    for (int kk = 0; kk < 2; ++kk) {
      bf16x8 afr = *(const bf16x8*)(pw + ((kk * 64 + l4 * 16) ^ sw));
#pragma unroll
      for (int i = 0; i < 4; ++i)
        ep[i] = __builtin_amdgcn_mfma_f32_16x16x32_bf16(sfr[kk][i], afr, ep[i], 0, 0, 0);
    }
    __builtin_amdgcn_s_setprio(0);
    float a = 0.f;
#pragma unroll
    for (int i = 0; i < 4; ++i)
#pragma unroll
      for (int p = 0; p < 4; ++p) a += fast_tanh(ep[i][p]) * sbv[i][p];
    a += __shfl_xor(a, 16);
    a += __shfl_xor(a, 32);

    // ---- exact online softmax update over active reviews ----
    // All surviving reviews have add_mask == 0, so e_r = a directly.
    const float e_r = a;
    const float mnew = fmaxf(m_run, e_r);
    const float scl = __expf(m_run - mnew);
    const float w = __expf(e_r - mnew);
    s_run = s_run * scl + w;
#pragma unroll
    for (int i = 0; i < 4; ++i)
#pragma unroll
      for (int p = 0; p < 4; ++p) Pacc[i][p] = Pacc[i][p] * scl + w * av[i][p];
    m_run = mnew;

    if (nr < 0) break;
    r = nr;
    rem &= rem - 1u;
    ++it;
  }

  // ---- merged[b*128+q][h*64+d] = bf16(Pacc / s) ----
  const float inv_s = __builtin_amdgcn_rcpf(s_run);
  unsigned short* mrow = merged + (size_t)(b * 128 + wave * 16 + lm) * 1024 + h * 64;
#pragma unroll
  for (int i = 0; i < 4; ++i) {
    uint2 o;
    o.x = pk2_rhu(Pacc[i][0] * inv_s, Pacc[i][1] * inv_s);
    o.y = pk2_rhu(Pacc[i][2] * inv_s, Pacc[i][3] * inv_s);
    *(uint2*)(mrow + i * 16 + l4 * 4) = o;
  }
}

// ---------------------------------------------------------------------------
extern "C" void kernel_launch(void* const* d_in, const int* in_sizes, int n_in,
                              void* d_out, int out_size, void* d_ws, size_t ws_size,
                              hipStream_t stream) {
  (void)in_sizes; (void)n_in; (void)out_size;
  const float* query = (const float*)d_in[0];
  const float* key   = (const float*)d_in[1];
  const float* value = (const float*)d_in[2];
  const int*   mask  = (const int*)d_in[3];
  const int*   mask2 = (const int*)d_in[4];
  const float* Wq = (const float*)d_in[5];
  const float* bq = (const float*)d_in[6];
  const float* Wk = (const float*)d_in[7];
  const float* bk = (const float*)d_in[8];
  const float* Wv = (const float*)d_in[9];
  const float* bv = (const float*)d_in[10];
  const float* Wo = (const float*)d_in[11];
  const float* bo = (const float*)d_in[12];
  const float* sa_a = (const float*)d_in[13];
  const float* sa_b = (const float*)d_in[14];

  char* ws = (char*)d_ws;
  size_t off = 0;
  auto carve = [&](size_t bytes) -> char* {
    char* p = ws + off;
    off += (bytes + 255) & ~(size_t)255;
    return p;
  };
  unsigned short* wq_b = (unsigned short*)carve((size_t)1024 * 1024 * 2);
  unsigned short* wk_b = (unsigned short*)carve((size_t)1024 * 1024 * 2);
  unsigned short* wv_b = (unsigned short*)carve((size_t)1024 * 1024 * 2);
  unsigned short* wo_b = (unsigned short*)carve((size_t)1024 * 1024 * 2);
  unsigned short* q_b  = (unsigned short*)carve((size_t)4096 * 1024 * 2);
  unsigned short* k_b  = (unsigned short*)carve((size_t)40960 * 1024 * 2);
  unsigned short* vt_g = (unsigned short*)carve((size_t)40960 * 1024 * 2);
  unsigned short* mrg  = (unsigned short*)carve((size_t)4096 * 1024 * 2);

  const size_t act_bytes = (size_t)40960 * 1024 * 2;
  const bool fat = ws_size >= off + act_bytes + (1 << 20);

  cvt_w4<<<1024, 256, 0, stream>>>(Wq, Wk, Wv, Wo, wq_b, wk_b, wv_b, wo_b);

  if (fat) {
    unsigned short* actb = (unsigned short*)carve(act_bytes);
    cvt_bf16<<<2048, 256, 0, stream>>>(query, actb, 4096 * 1024 / 8);
    gemm_bt<1, 1, 1><<<dim3(32 * 8), 256, 0, stream>>>(actb, wq_b, bq, q_b, 1024, 1024, 8);
    cvt_bf16<<<2048, 256, 0, stream>>>(key, actb, 40960 * 1024 / 8);
    gemm_bt<1, 1, 0><<<dim3(320 * 8), 256, 0, stream>>>(actb, wk_b, bk, k_b, 1024, 1024, 8);
    cvt_bf16<<<2048, 256, 0, stream>>>(value, actb, 40960 * 1024 / 8);
    gemm_bt<2, 1, 0><<<dim3(320 * 8), 256, 0, stream>>>(actb, wv_b, bv, vt_g, 1024, 1024, 8);
  } else {
    gemm_bt<1, 0, 1><<<dim3(32 * 8), 256, 0, stream>>>(query, wq_b, bq, q_b, 1024, 1024, 8);
    gemm_bt<1, 0, 0><<<dim3(320 * 8), 256, 0, stream>>>(key, wk_b, bk, k_b, 1024, 1024, 8);
    gemm_bt<2, 0, 0><<<dim3(320 * 8), 256, 0, stream>>>(value, wv_b, bv, vt_g, 1024, 1024, 8);
  }
  attn2<<<dim3(16, 32), 512, 0, stream>>>(q_b, k_b, vt_g, mask, mask2, sa_a, sa_b, mrg);
  gemm_bt<0, 1, 0><<<dim3(32 * 8), 256, 0, stream>>>(mrg, wo_b, bo, d_out, 1024, 1024, 8);
}